// Round 10
// baseline (151.283 us; speedup 1.0000x reference)
//
#include <hip/hip_runtime.h>
#include <stdint.h>

// ---------------------------------------------------------------------------
// TemporalCrossAttention: x[2048,16,512] -> out[2048,16,512] (fp32 in/out)
// Pipeline: fused transpose W->B^T bf16 | GEMM1 (A = f32 x, reg-staged cvt)
//           -> qkv head-major [8][32768][192] | attn | GEMM2 -> out
// GEMM1: 256x128 tile, 4 waves, BK=32, A reg-staged (f32->bf16 in flight,
// 3 LDS bufs), B gload_lds (3 bufs), prefetch dist 2, counted vmcnt(10).
// Workspace layout (bytes):
//   [0, 100663296)            qkv bf16 head-major [8][32768][192]
//   [100663296, 134217728)    attn_out bf16 [32768][512]
//   [134217728, 135790592)    WqkvT bf16 [1536][512]  (rows n = z*512+h*64+d)
//   [135790592, 136314880)    WoT   bf16 [512][512]
// ---------------------------------------------------------------------------

using bf16x8 = __attribute__((ext_vector_type(8))) short;
using f32x4  = __attribute__((ext_vector_type(4))) float;

#define AS3P(p) ((__attribute__((address_space(3))) void*)(p))
#define AS1P(p) ((const __attribute__((address_space(1))) void*)(p))

__device__ __forceinline__ uint16_t f2bf(float f) {
  unsigned int x = __builtin_bit_cast(unsigned int, f);
  x += 0x7fffu + ((x >> 16) & 1u);
  return (uint16_t)(x >> 16);
}
__device__ __forceinline__ uint32_t cvtpk(float lo, float hi) {
  uint32_t r;
  asm("v_cvt_pk_bf16_f32 %0, %1, %2" : "=v"(r) : "v"(lo), "v"(hi));
  return r;
}

// ------- fused transpose-cast: 4x [512][512] f32 -> dst[n][k]=src[k][n] bf16 -------
__global__ void transpose_cast4(const float* __restrict__ Wq, const float* __restrict__ Wk,
                                const float* __restrict__ Wv, const float* __restrict__ Wo,
                                uint16_t* __restrict__ WqkvT, uint16_t* __restrict__ WoT) {
  __shared__ float tile[32][33];
  const int z = blockIdx.z;
  const float* src = (z == 0) ? Wq : (z == 1) ? Wk : (z == 2) ? Wv : Wo;
  uint16_t* dst = (z == 3) ? WoT : (WqkvT + z * 262144);
  int tx = threadIdx.x, ty = threadIdx.y;           // (32,8)
  int c0 = blockIdx.x * 32, r0 = blockIdx.y * 32;
  #pragma unroll
  for (int k = 0; k < 4; ++k)
    tile[ty + 8 * k][tx] = src[(r0 + ty + 8 * k) * 512 + c0 + tx];
  __syncthreads();
  #pragma unroll
  for (int k = 0; k < 4; ++k)
    dst[(c0 + ty + 8 * k) * 512 + r0 + tx] = f2bf(tile[tx][ty + 8 * k]);
}

// ---------------- GEMM1: qkv = bf16(x_f32) @ WqkvT^T  (head-major out) ----------------
// 256x128 tile, 256 threads (4 waves = 2x2), per-wave 128x64, BK=32, NT=16.
// A: f32 global -> regs (issued 2 tiles early) -> cvt_pk -> swizzled ds_write.
// B: gload_lds via pre-swizzled source. Swizzle: 16B chunk of 128B row-pair at
// pos = (((row&1)<<2)|chunk) ^ ((row>>1)&7).
template<int KDIM>
__global__ __launch_bounds__(256, 2) void gemm1_f32a(
    const float* __restrict__ A, const uint16_t* __restrict__ B,
    uint16_t* __restrict__ C, int nbx) {
  constexpr int NT = KDIM / 32;   // 16
  __shared__ __align__(16) uint16_t ldsA[3][8192];   // 3 x 16KB
  __shared__ __align__(16) uint16_t ldsB[3][4096];   // 3 x 8KB
  __shared__ __align__(16) uint16_t ldsO[4][1024];   // 8KB epilogue transpose
  const int tid = threadIdx.x;
  const int w = tid >> 6, l = tid & 63;
  const int lr = l & 15, kc = l >> 4;
  const int wm = w >> 1, wn = w & 1;
  const int cpx = gridDim.x >> 3;
  const int id = blockIdx.x;
  const int swz = (id & 7) * cpx + (id >> 3);
  const int by = swz / nbx, bx = swz - by * nbx;
  const int mBase = by * 256, nBase = bx * 128;
  // A reg-staging: lane owns (row = w*64 + i*16 + (l>>2), chunk ac = l&3) for i=0..3
  const int ar = l >> 2, ac = l & 3;
  const float* gA = A + (size_t)(mBase + w * 64 + ar) * KDIM + ac * 8;
  // A ds_write byte offsets (swizzled), one per i
  int wofA[4];
  #pragma unroll
  for (int i = 0; i < 4; ++i) {
    int row = w * 64 + i * 16 + ar;
    int rp = row >> 1, sb = ((row & 1) << 2) | ac;
    wofA[i] = rp * 128 + ((sb ^ (rp & 7)) << 4);
  }
  // B staging source (pre-swizzled)
  const int g8 = l >> 3;
  const int sub = (l & 7) ^ g8;
  const uint16_t* gB = B + (size_t)(nBase + w * 32 + g8 * 2 + (sub >> 2)) * KDIM + (sub & 3) * 8;
  // ds_read byte offsets
  int offA[8], offB[4];
  #pragma unroll
  for (int m = 0; m < 8; ++m) {
    int row = wm * 128 + m * 16 + lr;
    int rp = row >> 1, sb = ((row & 1) << 2) | kc;
    offA[m] = rp * 128 + ((sb ^ (rp & 7)) << 4);
  }
  #pragma unroll
  for (int n = 0; n < 4; ++n) {
    int row = wn * 64 + n * 16 + lr;
    int rp = row >> 1, sb = ((row & 1) << 2) | kc;
    offB[n] = rp * 128 + ((sb ^ (rp & 7)) << 4);
  }
  f32x4 acc[8][4] = {};
  f32x4 ra[2][8];   // staging regs, double-buffered (static idx under full unroll)

#define LOAD_A(t, rb) do { \
    const float* s = gA + (t) * 32; \
    _Pragma("unroll") \
    for (int i = 0; i < 4; ++i) { \
      ra[rb][2 * i]     = *(const f32x4*)(s + i * 16 * KDIM); \
      ra[rb][2 * i + 1] = *(const f32x4*)(s + i * 16 * KDIM + 4); \
    } \
  } while (0)
#define WRITE_A(bf, rb) do { \
    uint16_t* d = &ldsA[bf][0]; \
    _Pragma("unroll") \
    for (int i = 0; i < 4; ++i) { \
      int4 q; \
      q.x = (int)cvtpk(ra[rb][2 * i][0], ra[rb][2 * i][1]); \
      q.y = (int)cvtpk(ra[rb][2 * i][2], ra[rb][2 * i][3]); \
      q.z = (int)cvtpk(ra[rb][2 * i + 1][0], ra[rb][2 * i + 1][1]); \
      q.w = (int)cvtpk(ra[rb][2 * i + 1][2], ra[rb][2 * i + 1][3]); \
      *(int4*)((char*)d + wofA[i]) = q; \
    } \
  } while (0)
#define STAGE_B(t, bf) do { \
    uint16_t* d = &ldsB[bf][w * 1024]; \
    const uint16_t* s = gB + (t) * 32; \
    __builtin_amdgcn_global_load_lds(AS1P(s),              AS3P(d),        16, 0, 0); \
    __builtin_amdgcn_global_load_lds(AS1P(s + 16 * KDIM),  AS3P(d + 512),  16, 0, 0); \
  } while (0)

  // prologue: A0 -> ra[0] -> ldsA[0]; then B0, A1 -> ra[1], B1; drain B0.
  LOAD_A(0, 0);
  asm volatile("s_waitcnt vmcnt(0)" ::: "memory");
  WRITE_A(0, 0);
  STAGE_B(0, 0);
  LOAD_A(1, 1);
  STAGE_B(1, 1);
  asm volatile("s_waitcnt vmcnt(10)" ::: "memory");   // drain B0 (A1,B1 in flight)
  asm volatile("s_waitcnt lgkmcnt(0)" ::: "memory");  // A0 ds_writes done
  __builtin_amdgcn_sched_barrier(0);
  __builtin_amdgcn_s_barrier();

  #pragma unroll
  for (int t = 0; t < NT; ++t) {
    const int bi = t % 3;
    const char* bufA = (const char*)&ldsA[bi][0];
    const char* bufB = (const char*)&ldsB[bi][0];
    // ---------------- phase 1 ----------------
    if (t + 2 < NT) LOAD_A(t + 2, t & 1);
    bf16x8 a0 = *(const bf16x8*)(bufA + offA[0]);
    bf16x8 a1 = *(const bf16x8*)(bufA + offA[1]);
    bf16x8 a2 = *(const bf16x8*)(bufA + offA[2]);
    bf16x8 a3 = *(const bf16x8*)(bufA + offA[3]);
    bf16x8 b0 = *(const bf16x8*)(bufB + offB[0]);
    bf16x8 b1 = *(const bf16x8*)(bufB + offB[1]);
    bf16x8 b2 = *(const bf16x8*)(bufB + offB[2]);
    bf16x8 b3 = *(const bf16x8*)(bufB + offB[3]);
    __builtin_amdgcn_sched_barrier(0);
    __builtin_amdgcn_s_barrier();
    asm volatile("s_waitcnt lgkmcnt(0)" ::: "memory");
    __builtin_amdgcn_sched_barrier(0);
    __builtin_amdgcn_s_setprio(1);
    acc[0][0] = __builtin_amdgcn_mfma_f32_16x16x32_bf16(a0, b0, acc[0][0], 0, 0, 0);
    acc[0][1] = __builtin_amdgcn_mfma_f32_16x16x32_bf16(a0, b1, acc[0][1], 0, 0, 0);
    acc[0][2] = __builtin_amdgcn_mfma_f32_16x16x32_bf16(a0, b2, acc[0][2], 0, 0, 0);
    acc[0][3] = __builtin_amdgcn_mfma_f32_16x16x32_bf16(a0, b3, acc[0][3], 0, 0, 0);
    acc[1][0] = __builtin_amdgcn_mfma_f32_16x16x32_bf16(a1, b0, acc[1][0], 0, 0, 0);
    acc[1][1] = __builtin_amdgcn_mfma_f32_16x16x32_bf16(a1, b1, acc[1][1], 0, 0, 0);
    acc[1][2] = __builtin_amdgcn_mfma_f32_16x16x32_bf16(a1, b2, acc[1][2], 0, 0, 0);
    acc[1][3] = __builtin_amdgcn_mfma_f32_16x16x32_bf16(a1, b3, acc[1][3], 0, 0, 0);
    acc[2][0] = __builtin_amdgcn_mfma_f32_16x16x32_bf16(a2, b0, acc[2][0], 0, 0, 0);
    acc[2][1] = __builtin_amdgcn_mfma_f32_16x16x32_bf16(a2, b1, acc[2][1], 0, 0, 0);
    acc[2][2] = __builtin_amdgcn_mfma_f32_16x16x32_bf16(a2, b2, acc[2][2], 0, 0, 0);
    acc[2][3] = __builtin_amdgcn_mfma_f32_16x16x32_bf16(a2, b3, acc[2][3], 0, 0, 0);
    acc[3][0] = __builtin_amdgcn_mfma_f32_16x16x32_bf16(a3, b0, acc[3][0], 0, 0, 0);
    acc[3][1] = __builtin_amdgcn_mfma_f32_16x16x32_bf16(a3, b1, acc[3][1], 0, 0, 0);
    acc[3][2] = __builtin_amdgcn_mfma_f32_16x16x32_bf16(a3, b2, acc[3][2], 0, 0, 0);
    acc[3][3] = __builtin_amdgcn_mfma_f32_16x16x32_bf16(a3, b3, acc[3][3], 0, 0, 0);
    __builtin_amdgcn_s_setprio(0);
    __builtin_amdgcn_sched_barrier(0);
    __builtin_amdgcn_s_barrier();
    // ---------------- phase 2 ----------------
    if (t + 2 < NT) STAGE_B(t + 2, (t + 2) % 3);
    bf16x8 a4 = *(const bf16x8*)(bufA + offA[4]);
    bf16x8 a5 = *(const bf16x8*)(bufA + offA[5]);
    bf16x8 a6 = *(const bf16x8*)(bufA + offA[6]);
    bf16x8 a7 = *(const bf16x8*)(bufA + offA[7]);
    // drain A(t+1) regs + B(t+1) gload_lds (leave t+2 traffic in flight)
    if (t + 2 < NT)      asm volatile("s_waitcnt vmcnt(10)" ::: "memory");
    else if (t + 1 < NT) asm volatile("s_waitcnt vmcnt(0)" ::: "memory");
    __builtin_amdgcn_sched_barrier(0);
    if (t + 1 < NT) WRITE_A((t + 1) % 3, (t + 1) & 1);
    __builtin_amdgcn_sched_barrier(0);
    __builtin_amdgcn_s_barrier();
    asm volatile("s_waitcnt lgkmcnt(0)" ::: "memory");
    __builtin_amdgcn_sched_barrier(0);
    __builtin_amdgcn_s_setprio(1);
    acc[4][0] = __builtin_amdgcn_mfma_f32_16x16x32_bf16(a4, b0, acc[4][0], 0, 0, 0);
    acc[4][1] = __builtin_amdgcn_mfma_f32_16x16x32_bf16(a4, b1, acc[4][1], 0, 0, 0);
    acc[4][2] = __builtin_amdgcn_mfma_f32_16x16x32_bf16(a4, b2, acc[4][2], 0, 0, 0);
    acc[4][3] = __builtin_amdgcn_mfma_f32_16x16x32_bf16(a4, b3, acc[4][3], 0, 0, 0);
    acc[5][0] = __builtin_amdgcn_mfma_f32_16x16x32_bf16(a5, b0, acc[5][0], 0, 0, 0);
    acc[5][1] = __builtin_amdgcn_mfma_f32_16x16x32_bf16(a5, b1, acc[5][1], 0, 0, 0);
    acc[5][2] = __builtin_amdgcn_mfma_f32_16x16x32_bf16(a5, b2, acc[5][2], 0, 0, 0);
    acc[5][3] = __builtin_amdgcn_mfma_f32_16x16x32_bf16(a5, b3, acc[5][3], 0, 0, 0);
    acc[6][0] = __builtin_amdgcn_mfma_f32_16x16x32_bf16(a6, b0, acc[6][0], 0, 0, 0);
    acc[6][1] = __builtin_amdgcn_mfma_f32_16x16x32_bf16(a6, b1, acc[6][1], 0, 0, 0);
    acc[6][2] = __builtin_amdgcn_mfma_f32_16x16x32_bf16(a6, b2, acc[6][2], 0, 0, 0);
    acc[6][3] = __builtin_amdgcn_mfma_f32_16x16x32_bf16(a6, b3, acc[6][3], 0, 0, 0);
    acc[7][0] = __builtin_amdgcn_mfma_f32_16x16x32_bf16(a7, b0, acc[7][0], 0, 0, 0);
    acc[7][1] = __builtin_amdgcn_mfma_f32_16x16x32_bf16(a7, b1, acc[7][1], 0, 0, 0);
    acc[7][2] = __builtin_amdgcn_mfma_f32_16x16x32_bf16(a7, b2, acc[7][2], 0, 0, 0);
    acc[7][3] = __builtin_amdgcn_mfma_f32_16x16x32_bf16(a7, b3, acc[7][3], 0, 0, 0);
    __builtin_amdgcn_s_setprio(0);
    __builtin_amdgcn_sched_barrier(0);
    __builtin_amdgcn_s_barrier();
  }
#undef LOAD_A
#undef WRITE_A
#undef STAGE_B
  // epilogue via per-wave LDS transpose -> coalesced b128 stores into
  // head-major qkv: grp = bx*2+wn, z = grp>>3, h = grp&7.
  {
    uint16_t* oW = &ldsO[w][0];
    const int t2 = l >> 3, c2 = l & 7;
    const int grp = bx * 2 + wn;
    const int z = grp >> 3, h = grp & 7;
    uint16_t* gO = C + (size_t)h * 6291456 +
                   (size_t)(mBase + wm * 128 + t2) * 192 + z * 64 + c2 * 8;
    #pragma unroll
    for (int m = 0; m < 8; ++m) {
      #pragma unroll
      for (int n = 0; n < 4; ++n)
        #pragma unroll
        for (int r = 0; r < 4; ++r) {
          const int tt = kc * 4 + r;
          const int d = n * 16 + lr;
          const int col = (((d >> 3) ^ (tt & 7)) << 3) | (d & 7);
          oW[tt * 64 + col] = f2bf(acc[m][n][r]);
        }
      asm volatile("s_waitcnt lgkmcnt(0)" ::: "memory");
      __builtin_amdgcn_sched_barrier(0);
      bf16x8 s0 = *(const bf16x8*)(oW + t2 * 64 + (((c2 ^ (t2 & 7)) << 3)));
      bf16x8 s1 = *(const bf16x8*)(oW + (8 + t2) * 64 + (((c2 ^ (t2 & 7)) << 3)));
      *(bf16x8*)(gO + (size_t)(m * 16) * 192) = s0;
      *(bf16x8*)(gO + (size_t)(m * 16 + 8) * 192) = s1;
      asm volatile("s_waitcnt lgkmcnt(0)" ::: "memory");
      __builtin_amdgcn_sched_barrier(0);
    }
  }
}

// ---------------- GEMM2: C[M,N](f32+bias) = A_bf16[M,K] * B_T[N,K]^T ----------------
// (round-8 validated kernel, OUT_MODE 0 path)
template<int KDIM>
__global__ __launch_bounds__(256, 2) void gemm256(
    const uint16_t* __restrict__ A, const uint16_t* __restrict__ B,
    float* __restrict__ C, const float* __restrict__ bias, int N, int nbx) {
  constexpr int NT = KDIM / 32;
  __shared__ __align__(16) uint16_t ldsA[3][8192];
  __shared__ __align__(16) uint16_t ldsB[3][4096];
  const int tid = threadIdx.x;
  const int w = tid >> 6, l = tid & 63;
  const int lr = l & 15, kc = l >> 4;
  const int wm = w >> 1, wn = w & 1;
  const int cpx = gridDim.x >> 3;
  const int id = blockIdx.x;
  const int swz = (id & 7) * cpx + (id >> 3);
  const int by = swz / nbx, bx = swz - by * nbx;
  const int mBase = by * 256, nBase = bx * 128;
  const int g8 = l >> 3;
  const int sub = (l & 7) ^ g8;
  const uint16_t* gA = A + (size_t)(mBase + w * 64 + g8 * 2 + (sub >> 2)) * KDIM + (sub & 3) * 8;
  const uint16_t* gB = B + (size_t)(nBase + w * 32 + g8 * 2 + (sub >> 2)) * KDIM + (sub & 3) * 8;
  int offA[8], offB[4];
  #pragma unroll
  for (int m = 0; m < 8; ++m) {
    int row = wm * 128 + m * 16 + lr;
    int rp = row >> 1, sb = ((row & 1) << 2) | kc;
    offA[m] = rp * 128 + ((sb ^ (rp & 7)) << 4);
  }
  #pragma unroll
  for (int n = 0; n < 4; ++n) {
    int row = wn * 64 + n * 16 + lr;
    int rp = row >> 1, sb = ((row & 1) << 2) | kc;
    offB[n] = rp * 128 + ((sb ^ (rp & 7)) << 4);
  }
  f32x4 acc[8][4] = {};
#define STAGE_A(t, bf) do { \
    uint16_t* d = &ldsA[bf][w * 2048]; \
    const uint16_t* s = gA + (t) * 32; \
    __builtin_amdgcn_global_load_lds(AS1P(s),              AS3P(d),        16, 0, 0); \
    __builtin_amdgcn_global_load_lds(AS1P(s + 16 * KDIM),  AS3P(d + 512),  16, 0, 0); \
    __builtin_amdgcn_global_load_lds(AS1P(s + 32 * KDIM),  AS3P(d + 1024), 16, 0, 0); \
    __builtin_amdgcn_global_load_lds(AS1P(s + 48 * KDIM),  AS3P(d + 1536), 16, 0, 0); \
  } while (0)
#define STAGE_B(t, bf) do { \
    uint16_t* d = &ldsB[bf][w * 1024]; \
    const uint16_t* s = gB + (t) * 32; \
    __builtin_amdgcn_global_load_lds(AS1P(s),              AS3P(d),        16, 0, 0); \
    __builtin_amdgcn_global_load_lds(AS1P(s + 16 * KDIM),  AS3P(d + 512),  16, 0, 0); \
  } while (0)
  STAGE_A(0, 0); STAGE_B(0, 0);
  STAGE_A(1, 1); STAGE_B(1, 1);
  asm volatile("s_waitcnt vmcnt(6)" ::: "memory");
  __builtin_amdgcn_s_barrier();
  #pragma unroll
  for (int t = 0; t < NT; ++t) {
    const int bi = t % 3;
    const int si = (t + 2) % 3;
    const char* bufA = (const char*)&ldsA[bi][0];
    const char* bufB = (const char*)&ldsB[bi][0];
    if (t + 2 < NT) STAGE_A(t + 2, si);
    if (t + 2 < NT) asm volatile("s_waitcnt vmcnt(4)" ::: "memory");
    else            asm volatile("s_waitcnt vmcnt(0)" ::: "memory");
    bf16x8 a0 = *(const bf16x8*)(bufA + offA[0]);
    bf16x8 a1 = *(const bf16x8*)(bufA + offA[1]);
    bf16x8 a2 = *(const bf16x8*)(bufA + offA[2]);
    bf16x8 a3 = *(const bf16x8*)(bufA + offA[3]);
    bf16x8 b0 = *(const bf16x8*)(bufB + offB[0]);
    bf16x8 b1 = *(const bf16x8*)(bufB + offB[1]);
    bf16x8 b2 = *(const bf16x8*)(bufB + offB[2]);
    bf16x8 b3 = *(const bf16x8*)(bufB + offB[3]);
    __builtin_amdgcn_sched_barrier(0);
    __builtin_amdgcn_s_barrier();
    asm volatile("s_waitcnt lgkmcnt(0)" ::: "memory");
    __builtin_amdgcn_sched_barrier(0);
    __builtin_amdgcn_s_setprio(1);
    acc[0][0] = __builtin_amdgcn_mfma_f32_16x16x32_bf16(a0, b0, acc[0][0], 0, 0, 0);
    acc[0][1] = __builtin_amdgcn_mfma_f32_16x16x32_bf16(a0, b1, acc[0][1], 0, 0, 0);
    acc[0][2] = __builtin_amdgcn_mfma_f32_16x16x32_bf16(a0, b2, acc[0][2], 0, 0, 0);
    acc[0][3] = __builtin_amdgcn_mfma_f32_16x16x32_bf16(a0, b3, acc[0][3], 0, 0, 0);
    acc[1][0] = __builtin_amdgcn_mfma_f32_16x16x32_bf16(a1, b0, acc[1][0], 0, 0, 0);
    acc[1][1] = __builtin_amdgcn_mfma_f32_16x16x32_bf16(a1, b1, acc[1][1], 0, 0, 0);
    acc[1][2] = __builtin_amdgcn_mfma_f32_16x16x32_bf16(a1, b2, acc[1][2], 0, 0, 0);
    acc[1][3] = __builtin_amdgcn_mfma_f32_16x16x32_bf16(a1, b3, acc[1][3], 0, 0, 0);
    acc[2][0] = __builtin_amdgcn_mfma_f32_16x16x32_bf16(a2, b0, acc[2][0], 0, 0, 0);
    acc[2][1] = __builtin_amdgcn_mfma_f32_16x16x32_bf16(a2, b1, acc[2][1], 0, 0, 0);
    acc[2][2] = __builtin_amdgcn_mfma_f32_16x16x32_bf16(a2, b2, acc[2][2], 0, 0, 0);
    acc[2][3] = __builtin_amdgcn_mfma_f32_16x16x32_bf16(a2, b3, acc[2][3], 0, 0, 0);
    acc[3][0] = __builtin_amdgcn_mfma_f32_16x16x32_bf16(a3, b0, acc[3][0], 0, 0, 0);
    acc[3][1] = __builtin_amdgcn_mfma_f32_16x16x32_bf16(a3, b1, acc[3][1], 0, 0, 0);
    acc[3][2] = __builtin_amdgcn_mfma_f32_16x16x32_bf16(a3, b2, acc[3][2], 0, 0, 0);
    acc[3][3] = __builtin_amdgcn_mfma_f32_16x16x32_bf16(a3, b3, acc[3][3], 0, 0, 0);
    __builtin_amdgcn_s_setprio(0);
    __builtin_amdgcn_sched_barrier(0);
    __builtin_amdgcn_s_barrier();
    if (t + 2 < NT) STAGE_B(t + 2, si);
    bf16x8 a4 = *(const bf16x8*)(bufA + offA[4]);
    bf16x8 a5 = *(const bf16x8*)(bufA + offA[5]);
    bf16x8 a6 = *(const bf16x8*)(bufA + offA[6]);
    bf16x8 a7 = *(const bf16x8*)(bufA + offA[7]);
    __builtin_amdgcn_sched_barrier(0);
    __builtin_amdgcn_s_barrier();
    asm volatile("s_waitcnt lgkmcnt(0)" ::: "memory");
    __builtin_amdgcn_sched_barrier(0);
    __builtin_amdgcn_s_setprio(1);
    acc[4][0] = __builtin_amdgcn_mfma_f32_16x16x32_bf16(a4, b0, acc[4][0], 0, 0, 0);
    acc[4][1] = __builtin_amdgcn_mfma_f32_16x16x32_bf16(a4, b1, acc[4][1], 0, 0, 0);
    acc[4][2] = __builtin_amdgcn_mfma_f32_16x16x32_bf16(a4, b2, acc[4][2], 0, 0, 0);
    acc[4][3] = __builtin_amdgcn_mfma_f32_16x16x32_bf16(a4, b3, acc[4][3], 0, 0, 0);
    acc[5][0] = __builtin_amdgcn_mfma_f32_16x16x32_bf16(a5, b0, acc[5][0], 0, 0, 0);
    acc[5][1] = __builtin_amdgcn_mfma_f32_16x16x32_bf16(a5, b1, acc[5][1], 0, 0, 0);
    acc[5][2] = __builtin_amdgcn_mfma_f32_16x16x32_bf16(a5, b2, acc[5][2], 0, 0, 0);
    acc[5][3] = __builtin_amdgcn_mfma_f32_16x16x32_bf16(a5, b3, acc[5][3], 0, 0, 0);
    acc[6][0] = __builtin_amdgcn_mfma_f32_16x16x32_bf16(a6, b0, acc[6][0], 0, 0, 0);
    acc[6][1] = __builtin_amdgcn_mfma_f32_16x16x32_bf16(a6, b1, acc[6][1], 0, 0, 0);
    acc[6][2] = __builtin_amdgcn_mfma_f32_16x16x32_bf16(a6, b2, acc[6][2], 0, 0, 0);
    acc[6][3] = __builtin_amdgcn_mfma_f32_16x16x32_bf16(a6, b3, acc[6][3], 0, 0, 0);
    acc[7][0] = __builtin_amdgcn_mfma_f32_16x16x32_bf16(a7, b0, acc[7][0], 0, 0, 0);
    acc[7][1] = __builtin_amdgcn_mfma_f32_16x16x32_bf16(a7, b1, acc[7][1], 0, 0, 0);
    acc[7][2] = __builtin_amdgcn_mfma_f32_16x16x32_bf16(a7, b2, acc[7][2], 0, 0, 0);
    acc[7][3] = __builtin_amdgcn_mfma_f32_16x16x32_bf16(a7, b3, acc[7][3], 0, 0, 0);
    __builtin_amdgcn_s_setprio(0);
    __builtin_amdgcn_sched_barrier(0);
    __builtin_amdgcn_s_barrier();
  }
#undef STAGE_A
#undef STAGE_B
  #pragma unroll
  for (int m = 0; m < 8; ++m)
    #pragma unroll
    for (int n = 0; n < 4; ++n) {
      const int col = nBase + wn * 64 + n * 16 + lr;
      #pragma unroll
      for (int r = 0; r < 4; ++r) {
        const int row = mBase + wm * 128 + m * 16 + kc * 4 + r;
        C[(size_t)row * N + col] = acc[m][n][r] + bias[col];
      }
    }
}

// ---------------- attention: 8 waves/block, one wave per (b,h) ----------------
__global__ __launch_bounds__(512) void attn_kernel(
    const uint16_t* __restrict__ qkv,
    const float* __restrict__ relk, const float* __restrict__ relv,
    uint16_t* __restrict__ outA) {
  __shared__ __align__(16) uint16_t relkS[33 * 72];
  __shared__ __align__(16) uint16_t relvT[64 * 40];
  __shared__ __align__(16) uint16_t vT[8][64 * 24];   // per-wave; reused as oW
  __shared__ float attnS[8][16 * 17];
  const int tid = threadIdx.x;
  for (int e = tid; e < 33 * 64; e += 512) {
    int j = e >> 6, d = e & 63;
    relkS[j * 72 + d] = f2bf(relk[e]);
    relvT[d * 40 + j] = f2bf(relv[e]);
  }
  const int w = tid >> 6, l = tid & 63;
  const int bh = blockIdx.x * 8 + w;
  const int b = bh >> 3, h = bh & 7;
  const int lr = l & 15, kc = l >> 4;
  const uint16_t* base = qkv + (size_t)h * 6291456 + (size_t)(b * 16) * 192;
  const uint16_t* qrow = base + lr * 192;
  bf16x8 aq0 = *(const bf16x8*)(qrow + kc * 8);
  bf16x8 aq1 = *(const bf16x8*)(qrow + 32 + kc * 8);
  const uint16_t* krow = qrow + 64;
  bf16x8 bk0 = *(const bf16x8*)(krow + kc * 8);
  bf16x8 bk1 = *(const bf16x8*)(krow + 32 + kc * 8);
  {
    const int s = l >> 2, dg = l & 3;
    const uint16_t* vrow = base + s * 192 + 128 + dg * 16;
    uint4 v0 = *(const uint4*)vrow;
    uint4 v1 = *(const uint4*)(vrow + 8);
    uint16_t tmp[16];
    *(uint4*)(tmp) = v0; *(uint4*)(tmp + 8) = v1;
    #pragma unroll
    for (int i = 0; i < 16; ++i)
      vT[w][(dg * 16 + i) * 24 + s] = tmp[i];
  }
  __syncthreads();
  const f32x4 zero = {0.f, 0.f, 0.f, 0.f};
  f32x4 sim = __builtin_amdgcn_mfma_f32_16x16x32_bf16(aq0, bk0, zero, 0, 0, 0);
  sim = __builtin_amdgcn_mfma_f32_16x16x32_bf16(aq1, bk1, sim, 0, 0, 0);
  bf16x8 rka0 = *(const bf16x8*)(relkS + lr * 72 + kc * 8);
  bf16x8 rka1 = *(const bf16x8*)(relkS + lr * 72 + 32 + kc * 8);
  bf16x8 rkb0 = *(const bf16x8*)(relkS + (16 + lr) * 72 + kc * 8);
  bf16x8 rkb1 = *(const bf16x8*)(relkS + (16 + lr) * 72 + 32 + kc * 8);
  f32x4 rqa = __builtin_amdgcn_mfma_f32_16x16x32_bf16(aq0, rka0, zero, 0, 0, 0);
  rqa = __builtin_amdgcn_mfma_f32_16x16x32_bf16(aq1, rka1, rqa, 0, 0, 0);
  f32x4 rqb = __builtin_amdgcn_mfma_f32_16x16x32_bf16(aq0, rkb0, zero, 0, 0, 0);
  rqb = __builtin_amdgcn_mfma_f32_16x16x32_bf16(aq1, rkb1, rqb, 0, 0, 0);
  #pragma unroll
  for (int r = 0; r < 4; ++r) {
    const int t = kc * 4 + r;
    const int j = lr - t + 16;
    const int src = (l & 48) | (j & 15);
    const float va = __shfl(rqa[r], src, 64);
    const float vb = __shfl(rqb[r], src, 64);
    const float rqv = (j < 16) ? va : vb;
    float sv = (sim[r] + rqv) * 0.125f;
    float m = sv;
    m = fmaxf(m, __shfl_xor(m, 1, 64));
    m = fmaxf(m, __shfl_xor(m, 2, 64));
    m = fmaxf(m, __shfl_xor(m, 4, 64));
    m = fmaxf(m, __shfl_xor(m, 8, 64));
    const float p = __expf(sv - m);
    float su = p;
    su += __shfl_xor(su, 1, 64);
    su += __shfl_xor(su, 2, 64);
    su += __shfl_xor(su, 4, 64);
    su += __shfl_xor(su, 8, 64);
    attnS[w][t * 17 + lr] = p / su;
  }
  __syncthreads();
  const float* aS = attnS[w];
  bf16x8 attnA, w2A;
  #pragma unroll
  for (int i = 0; i < 8; ++i) {
    const int s1 = kc * 8 + i;
    attnA[i] = (s1 < 16) ? (short)f2bf(aS[lr * 17 + s1]) : (short)0;
    const int s2 = s1 + lr - 16;
    w2A[i] = (s2 >= 0 && s2 < 16) ? (short)f2bf(aS[lr * 17 + s2]) : (short)0;
  }
  f32x4 o[4];
  #pragma unroll
  for (int dt = 0; dt < 4; ++dt) {
    bf16x8 vf  = *(const bf16x8*)(&vT[w][(dt * 16 + lr) * 24 + (kc & 1) * 8]);
    bf16x8 rvf = *(const bf16x8*)(&relvT[(dt * 16 + lr) * 40 + kc * 8]);
    o[dt] = __builtin_amdgcn_mfma_f32_16x16x32_bf16(w2A, rvf, zero, 0, 0, 0);
    o[dt] = __builtin_amdgcn_mfma_f32_16x16x32_bf16(attnA, vf, o[dt], 0, 0, 0);
  }
  asm volatile("s_waitcnt lgkmcnt(0)" ::: "memory");
  __builtin_amdgcn_sched_barrier(0);
  uint16_t* oW = &vT[w][0];
  #pragma unroll
  for (int dt = 0; dt < 4; ++dt)
    #pragma unroll
    for (int r = 0; r < 4; ++r) {
      const int t = kc * 4 + r;
      const int chunk = dt * 2 + (lr >> 3);
      oW[t * 64 + ((chunk ^ (t & 7)) << 3) + (lr & 7)] = f2bf(o[dt][r]);
    }
  asm volatile("s_waitcnt lgkmcnt(0)" ::: "memory");
  __builtin_amdgcn_sched_barrier(0);
  const int t2 = l >> 3, c2 = l & 7;
  bf16x8 s0 = *(const bf16x8*)(oW + t2 * 64 + ((c2 ^ (t2 & 7)) << 3));
  bf16x8 s1 = *(const bf16x8*)(oW + (8 + t2) * 64 + ((c2 ^ (t2 & 7)) << 3));
  *(bf16x8*)(outA + (size_t)(b * 16 + t2) * 512 + h * 64 + c2 * 8) = s0;
  *(bf16x8*)(outA + (size_t)(b * 16 + 8 + t2) * 512 + h * 64 + c2 * 8) = s1;
}

// ---------------------------------------------------------------------------
extern "C" void kernel_launch(void* const* d_in, const int* in_sizes, int n_in,
                              void* d_out, int out_size, void* d_ws, size_t ws_size,
                              hipStream_t stream) {
  const float* x    = (const float*)d_in[0];
  const float* Wq   = (const float*)d_in[1];
  const float* Wk   = (const float*)d_in[2];
  const float* Wv   = (const float*)d_in[3];
  const float* Wo   = (const float*)d_in[4];
  const float* bo   = (const float*)d_in[5];
  const float* relk = (const float*)d_in[6];
  const float* relv = (const float*)d_in[7];

  char* ws = (char*)d_ws;
  uint16_t* qkv   = (uint16_t*)ws;                    // head-major [8][32768][192]
  uint16_t* attnO = (uint16_t*)(ws + 100663296);      // [32768][512] bf16
  uint16_t* WqkvT = (uint16_t*)(ws + 134217728);      // [1536][512] bf16 (B^T)
  uint16_t* WoT   = (uint16_t*)(ws + 135790592);      // [512][512] bf16 (B^T)

  transpose_cast4<<<dim3(16, 16, 4), dim3(32, 8), 0, stream>>>(Wq, Wk, Wv, Wo, WqkvT, WoT);
  // qkv = bf16(x) @ [Wq|Wk|Wv]  (M=32768, N=1536, K=512), A read as f32
  gemm1_f32a<512><<<dim3(1536), dim3(256), 0, stream>>>(x, WqkvT, qkv, 12);
  // attention (reads head-major qkv, writes attn_out bf16 [32768][512])
  attn_kernel<<<2048, 512, 0, stream>>>(qkv, relk, relv, attnO);
  // out = attn_out @ Wo + bo  (fp32 out, M=32768, N=512, K=512)
  gemm256<512><<<dim3(512), dim3(256), 0, stream>>>(attnO, WoT, (float*)d_out, bo, 512, 4);
}

// Round 11
// 142.813 us; speedup vs baseline: 1.0593x; 1.0593x over previous
//
#include <hip/hip_runtime.h>
#include <stdint.h>

// ---------------------------------------------------------------------------
// TemporalCrossAttention: x[2048,16,512] -> out[2048,16,512] (fp32 in/out)
// Pipeline: cast x->bf16 | fused transpose W->B^T bf16 | GEMM1 -> qkv (head-
//           major [8][32768][192]) | attn (MFMA, 8 bh/block) | GEMM2 -> out
// GEMM: 256x128 tile, 4 waves (2x2), per-wave 128x64, BK=32, 3+3 LDS buffers
// (80KB -> 2 blocks/CU), prefetch distance 2, counted vmcnt(4).
// (Round-8 validated configuration; rounds 3/10 proved cast-fusion regresses.)
// Workspace layout (bytes):
//   [0, 100663296)            qkv bf16 head-major [8][32768][192]
//   [100663296, 134217728)    x_bf16 [32768][512]  (reused as attn_out)
//   [134217728, 135790592)    WqkvT bf16 [1536][512]  (rows n = z*512+h*64+d)
//   [135790592, 136314880)    WoT   bf16 [512][512]
// ---------------------------------------------------------------------------

using bf16x8 = __attribute__((ext_vector_type(8))) short;
using f32x4  = __attribute__((ext_vector_type(4))) float;

#define AS3P(p) ((__attribute__((address_space(3))) void*)(p))
#define AS1P(p) ((const __attribute__((address_space(1))) void*)(p))

__device__ __forceinline__ uint16_t f2bf(float f) {
  unsigned int x = __builtin_bit_cast(unsigned int, f);
  x += 0x7fffu + ((x >> 16) & 1u);
  return (uint16_t)(x >> 16);
}

// ---------------- cast x fp32 -> bf16 (8 elems/thread) ----------------
__global__ void cast_kernel(const float* __restrict__ in, uint16_t* __restrict__ out, int n8) {
  int i = blockIdx.x * 256 + threadIdx.x;
  if (i >= n8) return;
  float4 a = ((const float4*)in)[i * 2];
  float4 b = ((const float4*)in)[i * 2 + 1];
  uint4 r;
  r.x = (uint32_t)f2bf(a.x) | ((uint32_t)f2bf(a.y) << 16);
  r.y = (uint32_t)f2bf(a.z) | ((uint32_t)f2bf(a.w) << 16);
  r.z = (uint32_t)f2bf(b.x) | ((uint32_t)f2bf(b.y) << 16);
  r.w = (uint32_t)f2bf(b.z) | ((uint32_t)f2bf(b.w) << 16);
  ((uint4*)out)[i] = r;
}

// ------- fused transpose-cast: 4x [512][512] f32 -> dst[n][k]=src[k][n] bf16 -------
__global__ void transpose_cast4(const float* __restrict__ Wq, const float* __restrict__ Wk,
                                const float* __restrict__ Wv, const float* __restrict__ Wo,
                                uint16_t* __restrict__ WqkvT, uint16_t* __restrict__ WoT) {
  __shared__ float tile[32][33];
  const int z = blockIdx.z;
  const float* src = (z == 0) ? Wq : (z == 1) ? Wk : (z == 2) ? Wv : Wo;
  uint16_t* dst = (z == 3) ? WoT : (WqkvT + z * 262144);
  int tx = threadIdx.x, ty = threadIdx.y;           // (32,8)
  int c0 = blockIdx.x * 32, r0 = blockIdx.y * 32;
  #pragma unroll
  for (int k = 0; k < 4; ++k)
    tile[ty + 8 * k][tx] = src[(r0 + ty + 8 * k) * 512 + c0 + tx];
  __syncthreads();
  #pragma unroll
  for (int k = 0; k < 4; ++k)
    dst[(c0 + ty + 8 * k) * 512 + r0 + tx] = f2bf(tile[tx][ty + 8 * k]);
}

// ---------------- GEMM: C[M,N] = A[M,K] * B_T[N,K]^T  (bf16 in) ----------------
// 256x128 tile, 256 threads (4 waves = 2 wm x 2 wn), per-wave C block 128x64.
// K-tiles of BK=32; 3 A-bufs + 3 B-bufs rotate; prefetch distance 2; counted
// vmcnt(4).  LDS swizzle (both sides): within a 128B row-pair, 16B chunk at
// logical (row,chunk) lives at pos = (((row&1)<<2)|chunk) ^ ((row>>1)&7).
// OUT_MODE 1: bf16 out to HEAD-MAJOR qkv [8][32768][192]: 64-col group
//   grp = bx*2+wn -> z=grp>>3 (q/k/v), h=grp&7; addr = h*6291456 + row*192 + z*64.
// OUT_MODE 0: f32 + bias, standard [M][N].
template<int OUT_MODE, int KDIM>
__global__ __launch_bounds__(256, 2) void gemm256(
    const uint16_t* __restrict__ A, const uint16_t* __restrict__ B,
    void* __restrict__ C, const float* __restrict__ bias, int N, int nbx) {
  constexpr int NT = KDIM / 32;
  __shared__ __align__(16) uint16_t ldsA[3][8192];   // 3 x 16KB
  __shared__ __align__(16) uint16_t ldsB[3][4096];   // 3 x 8KB
  __shared__ __align__(16) uint16_t ldsO[4][1024];   // 8KB epilogue transpose
  const int tid = threadIdx.x;
  const int w = tid >> 6, l = tid & 63;
  const int lr = l & 15, kc = l >> 4;
  const int wm = w >> 1, wn = w & 1;
  const int cpx = gridDim.x >> 3;
  const int id = blockIdx.x;
  const int swz = (id & 7) * cpx + (id >> 3);
  const int by = swz / nbx, bx = swz - by * nbx;
  const int mBase = by * 256, nBase = bx * 128;
  // staging source (pre-swizzled): dest lane l writes 16B at linear pos l;
  // row-pair rp = l>>3, slot p = l&7; logical ((row&1)<<2)|chunk = p ^ (rp&7).
  const int g8 = l >> 3;
  const int sub = (l & 7) ^ g8;
  const uint16_t* gA = A + (size_t)(mBase + w * 64 + g8 * 2 + (sub >> 2)) * KDIM + (sub & 3) * 8;
  const uint16_t* gB = B + (size_t)(nBase + w * 32 + g8 * 2 + (sub >> 2)) * KDIM + (sub & 3) * 8;
  int offA[8], offB[4];
  #pragma unroll
  for (int m = 0; m < 8; ++m) {
    int row = wm * 128 + m * 16 + lr;
    int rp = row >> 1, sb = ((row & 1) << 2) | kc;
    offA[m] = rp * 128 + ((sb ^ (rp & 7)) << 4);
  }
  #pragma unroll
  for (int n = 0; n < 4; ++n) {
    int row = wn * 64 + n * 16 + lr;
    int rp = row >> 1, sb = ((row & 1) << 2) | kc;
    offB[n] = rp * 128 + ((sb ^ (rp & 7)) << 4);
  }
  f32x4 acc[8][4] = {};

#define STAGE_A(t, bf) do { \
    uint16_t* d = &ldsA[bf][w * 2048]; \
    const uint16_t* s = gA + (t) * 32; \
    __builtin_amdgcn_global_load_lds(AS1P(s),              AS3P(d),        16, 0, 0); \
    __builtin_amdgcn_global_load_lds(AS1P(s + 16 * KDIM),  AS3P(d + 512),  16, 0, 0); \
    __builtin_amdgcn_global_load_lds(AS1P(s + 32 * KDIM),  AS3P(d + 1024), 16, 0, 0); \
    __builtin_amdgcn_global_load_lds(AS1P(s + 48 * KDIM),  AS3P(d + 1536), 16, 0, 0); \
  } while (0)
#define STAGE_B(t, bf) do { \
    uint16_t* d = &ldsB[bf][w * 1024]; \
    const uint16_t* s = gB + (t) * 32; \
    __builtin_amdgcn_global_load_lds(AS1P(s),              AS3P(d),        16, 0, 0); \
    __builtin_amdgcn_global_load_lds(AS1P(s + 16 * KDIM),  AS3P(d + 512),  16, 0, 0); \
  } while (0)

  // prologue: tiles 0,1 (A0,B0,A1,B1 = 12 loads); vmcnt(6) -> tile 0 resident
  STAGE_A(0, 0); STAGE_B(0, 0);
  STAGE_A(1, 1); STAGE_B(1, 1);
  asm volatile("s_waitcnt vmcnt(6)" ::: "memory");
  __builtin_amdgcn_s_barrier();

  #pragma unroll
  for (int t = 0; t < NT; ++t) {
    const int bi = t % 3;
    const int si = (t + 2) % 3;
    const char* bufA = (const char*)&ldsA[bi][0];
    const char* bufB = (const char*)&ldsB[bi][0];
    // ---------------- phase 1 ----------------
    if (t + 2 < NT) STAGE_A(t + 2, si);
    // counted wait: tile t+1 resident (own loads; barrier propagates cross-wave)
    if (t + 2 < NT) asm volatile("s_waitcnt vmcnt(4)" ::: "memory");
    else            asm volatile("s_waitcnt vmcnt(0)" ::: "memory");
    bf16x8 a0 = *(const bf16x8*)(bufA + offA[0]);
    bf16x8 a1 = *(const bf16x8*)(bufA + offA[1]);
    bf16x8 a2 = *(const bf16x8*)(bufA + offA[2]);
    bf16x8 a3 = *(const bf16x8*)(bufA + offA[3]);
    bf16x8 b0 = *(const bf16x8*)(bufB + offB[0]);
    bf16x8 b1 = *(const bf16x8*)(bufB + offB[1]);
    bf16x8 b2 = *(const bf16x8*)(bufB + offB[2]);
    bf16x8 b3 = *(const bf16x8*)(bufB + offB[3]);
    __builtin_amdgcn_sched_barrier(0);
    __builtin_amdgcn_s_barrier();
    asm volatile("s_waitcnt lgkmcnt(0)" ::: "memory");
    __builtin_amdgcn_sched_barrier(0);
    __builtin_amdgcn_s_setprio(1);
    acc[0][0] = __builtin_amdgcn_mfma_f32_16x16x32_bf16(a0, b0, acc[0][0], 0, 0, 0);
    acc[0][1] = __builtin_amdgcn_mfma_f32_16x16x32_bf16(a0, b1, acc[0][1], 0, 0, 0);
    acc[0][2] = __builtin_amdgcn_mfma_f32_16x16x32_bf16(a0, b2, acc[0][2], 0, 0, 0);
    acc[0][3] = __builtin_amdgcn_mfma_f32_16x16x32_bf16(a0, b3, acc[0][3], 0, 0, 0);
    acc[1][0] = __builtin_amdgcn_mfma_f32_16x16x32_bf16(a1, b0, acc[1][0], 0, 0, 0);
    acc[1][1] = __builtin_amdgcn_mfma_f32_16x16x32_bf16(a1, b1, acc[1][1], 0, 0, 0);
    acc[1][2] = __builtin_amdgcn_mfma_f32_16x16x32_bf16(a1, b2, acc[1][2], 0, 0, 0);
    acc[1][3] = __builtin_amdgcn_mfma_f32_16x16x32_bf16(a1, b3, acc[1][3], 0, 0, 0);
    acc[2][0] = __builtin_amdgcn_mfma_f32_16x16x32_bf16(a2, b0, acc[2][0], 0, 0, 0);
    acc[2][1] = __builtin_amdgcn_mfma_f32_16x16x32_bf16(a2, b1, acc[2][1], 0, 0, 0);
    acc[2][2] = __builtin_amdgcn_mfma_f32_16x16x32_bf16(a2, b2, acc[2][2], 0, 0, 0);
    acc[2][3] = __builtin_amdgcn_mfma_f32_16x16x32_bf16(a2, b3, acc[2][3], 0, 0, 0);
    acc[3][0] = __builtin_amdgcn_mfma_f32_16x16x32_bf16(a3, b0, acc[3][0], 0, 0, 0);
    acc[3][1] = __builtin_amdgcn_mfma_f32_16x16x32_bf16(a3, b1, acc[3][1], 0, 0, 0);
    acc[3][2] = __builtin_amdgcn_mfma_f32_16x16x32_bf16(a3, b2, acc[3][2], 0, 0, 0);
    acc[3][3] = __builtin_amdgcn_mfma_f32_16x16x32_bf16(a3, b3, acc[3][3], 0, 0, 0);
    __builtin_amdgcn_s_setprio(0);
    __builtin_amdgcn_sched_barrier(0);
    __builtin_amdgcn_s_barrier();
    // ---------------- phase 2 ----------------
    if (t + 2 < NT) STAGE_B(t + 2, si);
    bf16x8 a4 = *(const bf16x8*)(bufA + offA[4]);
    bf16x8 a5 = *(const bf16x8*)(bufA + offA[5]);
    bf16x8 a6 = *(const bf16x8*)(bufA + offA[6]);
    bf16x8 a7 = *(const bf16x8*)(bufA + offA[7]);
    __builtin_amdgcn_sched_barrier(0);
    __builtin_amdgcn_s_barrier();
    asm volatile("s_waitcnt lgkmcnt(0)" ::: "memory");
    __builtin_amdgcn_sched_barrier(0);
    __builtin_amdgcn_s_setprio(1);
    acc[4][0] = __builtin_amdgcn_mfma_f32_16x16x32_bf16(a4, b0, acc[4][0], 0, 0, 0);
    acc[4][1] = __builtin_amdgcn_mfma_f32_16x16x32_bf16(a4, b1, acc[4][1], 0, 0, 0);
    acc[4][2] = __builtin_amdgcn_mfma_f32_16x16x32_bf16(a4, b2, acc[4][2], 0, 0, 0);
    acc[4][3] = __builtin_amdgcn_mfma_f32_16x16x32_bf16(a4, b3, acc[4][3], 0, 0, 0);
    acc[5][0] = __builtin_amdgcn_mfma_f32_16x16x32_bf16(a5, b0, acc[5][0], 0, 0, 0);
    acc[5][1] = __builtin_amdgcn_mfma_f32_16x16x32_bf16(a5, b1, acc[5][1], 0, 0, 0);
    acc[5][2] = __builtin_amdgcn_mfma_f32_16x16x32_bf16(a5, b2, acc[5][2], 0, 0, 0);
    acc[5][3] = __builtin_amdgcn_mfma_f32_16x16x32_bf16(a5, b3, acc[5][3], 0, 0, 0);
    acc[6][0] = __builtin_amdgcn_mfma_f32_16x16x32_bf16(a6, b0, acc[6][0], 0, 0, 0);
    acc[6][1] = __builtin_amdgcn_mfma_f32_16x16x32_bf16(a6, b1, acc[6][1], 0, 0, 0);
    acc[6][2] = __builtin_amdgcn_mfma_f32_16x16x32_bf16(a6, b2, acc[6][2], 0, 0, 0);
    acc[6][3] = __builtin_amdgcn_mfma_f32_16x16x32_bf16(a6, b3, acc[6][3], 0, 0, 0);
    acc[7][0] = __builtin_amdgcn_mfma_f32_16x16x32_bf16(a7, b0, acc[7][0], 0, 0, 0);
    acc[7][1] = __builtin_amdgcn_mfma_f32_16x16x32_bf16(a7, b1, acc[7][1], 0, 0, 0);
    acc[7][2] = __builtin_amdgcn_mfma_f32_16x16x32_bf16(a7, b2, acc[7][2], 0, 0, 0);
    acc[7][3] = __builtin_amdgcn_mfma_f32_16x16x32_bf16(a7, b3, acc[7][3], 0, 0, 0);
    __builtin_amdgcn_s_setprio(0);
    __builtin_amdgcn_sched_barrier(0);
    __builtin_amdgcn_s_barrier();
  }
#undef STAGE_A
#undef STAGE_B
  if (OUT_MODE == 1) {
    // epilogue via per-wave LDS transpose -> coalesced b128 stores into
    // head-major qkv: grp = bx*2+wn (64-col group), z = grp>>3, h = grp&7.
    uint16_t* oW = &ldsO[w][0];
    const int t2 = l >> 3, c2 = l & 7;
    const int grp = bx * 2 + wn;
    const int z = grp >> 3, h = grp & 7;
    uint16_t* gO = (uint16_t*)C + (size_t)h * 6291456 +
                   (size_t)(mBase + wm * 128 + t2) * 192 + z * 64 + c2 * 8;
    #pragma unroll
    for (int m = 0; m < 8; ++m) {
      #pragma unroll
      for (int n = 0; n < 4; ++n)
        #pragma unroll
        for (int r = 0; r < 4; ++r) {
          const int tt = kc * 4 + r;
          const int d = n * 16 + lr;
          const int col = (((d >> 3) ^ (tt & 7)) << 3) | (d & 7);
          oW[tt * 64 + col] = f2bf(acc[m][n][r]);
        }
      asm volatile("s_waitcnt lgkmcnt(0)" ::: "memory");
      __builtin_amdgcn_sched_barrier(0);
      bf16x8 s0 = *(const bf16x8*)(oW + t2 * 64 + (((c2 ^ (t2 & 7)) << 3)));
      bf16x8 s1 = *(const bf16x8*)(oW + (8 + t2) * 64 + (((c2 ^ (t2 & 7)) << 3)));
      *(bf16x8*)(gO + (size_t)(m * 16) * 192) = s0;
      *(bf16x8*)(gO + (size_t)(m * 16 + 8) * 192) = s1;
      asm volatile("s_waitcnt lgkmcnt(0)" ::: "memory");
      __builtin_amdgcn_sched_barrier(0);
    }
  } else {
    #pragma unroll
    for (int m = 0; m < 8; ++m)
      #pragma unroll
      for (int n = 0; n < 4; ++n) {
        const int col = nBase + wn * 64 + n * 16 + lr;
        #pragma unroll
        for (int r = 0; r < 4; ++r) {
          const int row = mBase + wm * 128 + m * 16 + kc * 4 + r;
          ((float*)C)[(size_t)row * N + col] = acc[m][n][r] + bias[col];
        }
      }
  }
}

// ---------------- attention: 8 waves/block, one wave per (b,h) ----------------
// qkv head-major [8][32768][192]: per (b,h) the 16 rows are contiguous 384B
// chunks (q bytes [0,128), k [128,256), v [256,384)).
__global__ __launch_bounds__(512) void attn_kernel(
    const uint16_t* __restrict__ qkv,
    const float* __restrict__ relk, const float* __restrict__ relv,
    uint16_t* __restrict__ outA) {
  __shared__ __align__(16) uint16_t relkS[33 * 72];
  __shared__ __align__(16) uint16_t relvT[64 * 40];
  __shared__ __align__(16) uint16_t vT[8][64 * 24];   // per-wave; reused as oW
  __shared__ float attnS[8][16 * 17];
  const int tid = threadIdx.x;
  for (int e = tid; e < 33 * 64; e += 512) {
    int j = e >> 6, d = e & 63;
    relkS[j * 72 + d] = f2bf(relk[e]);
    relvT[d * 40 + j] = f2bf(relv[e]);
  }
  const int w = tid >> 6, l = tid & 63;
  const int bh = blockIdx.x * 8 + w;
  const int b = bh >> 3, h = bh & 7;
  const int lr = l & 15, kc = l >> 4;
  const uint16_t* base = qkv + (size_t)h * 6291456 + (size_t)(b * 16) * 192;
  const uint16_t* qrow = base + lr * 192;
  bf16x8 aq0 = *(const bf16x8*)(qrow + kc * 8);
  bf16x8 aq1 = *(const bf16x8*)(qrow + 32 + kc * 8);
  const uint16_t* krow = qrow + 64;
  bf16x8 bk0 = *(const bf16x8*)(krow + kc * 8);
  bf16x8 bk1 = *(const bf16x8*)(krow + 32 + kc * 8);
  {
    const int s = l >> 2, dg = l & 3;
    const uint16_t* vrow = base + s * 192 + 128 + dg * 16;
    uint4 v0 = *(const uint4*)vrow;
    uint4 v1 = *(const uint4*)(vrow + 8);
    uint16_t tmp[16];
    *(uint4*)(tmp) = v0; *(uint4*)(tmp + 8) = v1;
    #pragma unroll
    for (int i = 0; i < 16; ++i)
      vT[w][(dg * 16 + i) * 24 + s] = tmp[i];
  }
  __syncthreads();
  const f32x4 zero = {0.f, 0.f, 0.f, 0.f};
  f32x4 sim = __builtin_amdgcn_mfma_f32_16x16x32_bf16(aq0, bk0, zero, 0, 0, 0);
  sim = __builtin_amdgcn_mfma_f32_16x16x32_bf16(aq1, bk1, sim, 0, 0, 0);
  bf16x8 rka0 = *(const bf16x8*)(relkS + lr * 72 + kc * 8);
  bf16x8 rka1 = *(const bf16x8*)(relkS + lr * 72 + 32 + kc * 8);
  bf16x8 rkb0 = *(const bf16x8*)(relkS + (16 + lr) * 72 + kc * 8);
  bf16x8 rkb1 = *(const bf16x8*)(relkS + (16 + lr) * 72 + 32 + kc * 8);
  f32x4 rqa = __builtin_amdgcn_mfma_f32_16x16x32_bf16(aq0, rka0, zero, 0, 0, 0);
  rqa = __builtin_amdgcn_mfma_f32_16x16x32_bf16(aq1, rka1, rqa, 0, 0, 0);
  f32x4 rqb = __builtin_amdgcn_mfma_f32_16x16x32_bf16(aq0, rkb0, zero, 0, 0, 0);
  rqb = __builtin_amdgcn_mfma_f32_16x16x32_bf16(aq1, rkb1, rqb, 0, 0, 0);
  #pragma unroll
  for (int r = 0; r < 4; ++r) {
    const int t = kc * 4 + r;
    const int j = lr - t + 16;
    const int src = (l & 48) | (j & 15);
    const float va = __shfl(rqa[r], src, 64);
    const float vb = __shfl(rqb[r], src, 64);
    const float rqv = (j < 16) ? va : vb;
    float sv = (sim[r] + rqv) * 0.125f;
    float m = sv;
    m = fmaxf(m, __shfl_xor(m, 1, 64));
    m = fmaxf(m, __shfl_xor(m, 2, 64));
    m = fmaxf(m, __shfl_xor(m, 4, 64));
    m = fmaxf(m, __shfl_xor(m, 8, 64));
    const float p = __expf(sv - m);
    float su = p;
    su += __shfl_xor(su, 1, 64);
    su += __shfl_xor(su, 2, 64);
    su += __shfl_xor(su, 4, 64);
    su += __shfl_xor(su, 8, 64);
    attnS[w][t * 17 + lr] = p / su;
  }
  __syncthreads();
  const float* aS = attnS[w];
  bf16x8 attnA, w2A;
  #pragma unroll
  for (int i = 0; i < 8; ++i) {
    const int s1 = kc * 8 + i;
    attnA[i] = (s1 < 16) ? (short)f2bf(aS[lr * 17 + s1]) : (short)0;
    const int s2 = s1 + lr - 16;
    w2A[i] = (s2 >= 0 && s2 < 16) ? (short)f2bf(aS[lr * 17 + s2]) : (short)0;
  }
  f32x4 o[4];
  #pragma unroll
  for (int dt = 0; dt < 4; ++dt) {
    bf16x8 vf  = *(const bf16x8*)(&vT[w][(dt * 16 + lr) * 24 + (kc & 1) * 8]);
    bf16x8 rvf = *(const bf16x8*)(&relvT[(dt * 16 + lr) * 40 + kc * 8]);
    o[dt] = __builtin_amdgcn_mfma_f32_16x16x32_bf16(w2A, rvf, zero, 0, 0, 0);
    o[dt] = __builtin_amdgcn_mfma_f32_16x16x32_bf16(attnA, vf, o[dt], 0, 0, 0);
  }
  // coalesced store: transpose [16][64] through LDS (overlaid on dead vT[w])
  asm volatile("s_waitcnt lgkmcnt(0)" ::: "memory");
  __builtin_amdgcn_sched_barrier(0);
  uint16_t* oW = &vT[w][0];
  #pragma unroll
  for (int dt = 0; dt < 4; ++dt)
    #pragma unroll
    for (int r = 0; r < 4; ++r) {
      const int t = kc * 4 + r;
      const int chunk = dt * 2 + (lr >> 3);
      oW[t * 64 + ((chunk ^ (t & 7)) << 3) + (lr & 7)] = f2bf(o[dt][r]);
    }
  asm volatile("s_waitcnt lgkmcnt(0)" ::: "memory");
  __builtin_amdgcn_sched_barrier(0);
  const int t2 = l >> 3, c2 = l & 7;
  bf16x8 s0 = *(const bf16x8*)(oW + t2 * 64 + ((c2 ^ (t2 & 7)) << 3));
  bf16x8 s1 = *(const bf16x8*)(oW + (8 + t2) * 64 + ((c2 ^ (t2 & 7)) << 3));
  *(bf16x8*)(outA + (size_t)(b * 16 + t2) * 512 + h * 64 + c2 * 8) = s0;
  *(bf16x8*)(outA + (size_t)(b * 16 + 8 + t2) * 512 + h * 64 + c2 * 8) = s1;
}

// ---------------------------------------------------------------------------
extern "C" void kernel_launch(void* const* d_in, const int* in_sizes, int n_in,
                              void* d_out, int out_size, void* d_ws, size_t ws_size,
                              hipStream_t stream) {
  const float* x    = (const float*)d_in[0];
  const float* Wq   = (const float*)d_in[1];
  const float* Wk   = (const float*)d_in[2];
  const float* Wv   = (const float*)d_in[3];
  const float* Wo   = (const float*)d_in[4];
  const float* bo   = (const float*)d_in[5];
  const float* relk = (const float*)d_in[6];
  const float* relv = (const float*)d_in[7];

  char* ws = (char*)d_ws;
  uint16_t* qkv   = (uint16_t*)ws;                    // head-major [8][32768][192]
  uint16_t* xbf   = (uint16_t*)(ws + 100663296);      // [32768][512] bf16
  uint16_t* WqkvT = (uint16_t*)(ws + 134217728);      // [1536][512] bf16 (B^T)
  uint16_t* WoT   = (uint16_t*)(ws + 135790592);      // [512][512] bf16 (B^T)
  uint16_t* attnO = xbf;                              // reuse: x_bf dead after GEMM1

  cast_kernel<<<8192, 256, 0, stream>>>(x, xbf, 2097152);
  transpose_cast4<<<dim3(16, 16, 4), dim3(32, 8), 0, stream>>>(Wq, Wk, Wv, Wo, WqkvT, WoT);
  // qkv = x_bf @ [Wq|Wk|Wv]  (M=32768, N=1536, K=512), head-major bf16 out
  gemm256<1, 512><<<dim3(1536), dim3(256), 0, stream>>>(xbf, WqkvT, (void*)qkv, nullptr, 1536, 12);
  // attention (reads head-major qkv, writes attn_out bf16 [32768][512])
  attn_kernel<<<2048, 512, 0, stream>>>(qkv, relk, relv, attnO);
  // out = attn_out @ Wo + bo  (fp32 out, M=32768, N=512, K=512)
  gemm256<0, 512><<<dim3(512), dim3(256), 0, stream>>>(attnO, WoT, d_out, bo, 512, 4);
}

// Round 12
// 135.329 us; speedup vs baseline: 1.1179x; 1.0553x over previous
//
#include <hip/hip_runtime.h>
#include <stdint.h>

// ---------------------------------------------------------------------------
// TemporalCrossAttention: x[2048,16,512] -> out[2048,16,512] (fp32 in/out)
// Pipeline: prep (cast x->bf16 ∥ transpose W->B^T bf16, one launch) |
//           GEMM1 -> qkv head-major [8][32768][192] | attn (4 blocks/CU) |
//           GEMM2 -> out
// GEMM: 256x128 tile, 4 waves (2x2), per-wave 128x64, BK=32, 3+3 LDS buffers
// (80KB -> 2 blocks/CU), prefetch distance 2, counted vmcnt(4).
// Workspace layout (bytes):
//   [0, 100663296)            qkv bf16 head-major [8][32768][192]
//   [100663296, 134217728)    x_bf16 [32768][512]  (reused as attn_out)
//   [134217728, 135790592)    WqkvT bf16 [1536][512]  (rows n = z*512+h*64+d)
//   [135790592, 136314880)    WoT   bf16 [512][512]
// ---------------------------------------------------------------------------

using bf16x8 = __attribute__((ext_vector_type(8))) short;
using f32x4  = __attribute__((ext_vector_type(4))) float;

#define AS3P(p) ((__attribute__((address_space(3))) void*)(p))
#define AS1P(p) ((const __attribute__((address_space(1))) void*)(p))

__device__ __forceinline__ uint16_t f2bf(float f) {
  unsigned int x = __builtin_bit_cast(unsigned int, f);
  x += 0x7fffu + ((x >> 16) & 1u);
  return (uint16_t)(x >> 16);
}

// ---- prep: blocks 0..8191 cast x f32->bf16 (8 elem/thread); blocks
// 8192..9215 transpose-cast the 4 weight matrices (flattened 16x16x4 grid) ----
__global__ __launch_bounds__(256) void prep_kernel(
    const float* __restrict__ x, uint16_t* __restrict__ xbf,
    const float* __restrict__ Wq, const float* __restrict__ Wk,
    const float* __restrict__ Wv, const float* __restrict__ Wo,
    uint16_t* __restrict__ WqkvT, uint16_t* __restrict__ WoT) {
  __shared__ float tile[32][33];
  const int bid = blockIdx.x;
  const int tid = threadIdx.x;
  if (bid < 8192) {
    const int i = bid * 256 + tid;            // n8 = 2097152 = 8192*256 exactly
    float4 a = ((const float4*)x)[i * 2];
    float4 b = ((const float4*)x)[i * 2 + 1];
    uint4 r;
    r.x = (uint32_t)f2bf(a.x) | ((uint32_t)f2bf(a.y) << 16);
    r.y = (uint32_t)f2bf(a.z) | ((uint32_t)f2bf(a.w) << 16);
    r.z = (uint32_t)f2bf(b.x) | ((uint32_t)f2bf(b.y) << 16);
    r.w = (uint32_t)f2bf(b.z) | ((uint32_t)f2bf(b.w) << 16);
    ((uint4*)xbf)[i] = r;
    return;
  }
  const int wb = bid - 8192;                  // 1024 blocks: z*256 + by*16 + bx
  const int z = wb >> 8;
  const int r0 = ((wb >> 4) & 15) * 32;
  const int c0 = (wb & 15) * 32;
  const float* src = (z == 0) ? Wq : (z == 1) ? Wk : (z == 2) ? Wv : Wo;
  uint16_t* dst = (z == 3) ? WoT : (WqkvT + z * 262144);
  const int tx = tid & 31, ty = tid >> 5;     // (32,8)
  #pragma unroll
  for (int k = 0; k < 4; ++k)
    tile[ty + 8 * k][tx] = src[(r0 + ty + 8 * k) * 512 + c0 + tx];
  __syncthreads();
  #pragma unroll
  for (int k = 0; k < 4; ++k)
    dst[(c0 + ty + 8 * k) * 512 + r0 + tx] = f2bf(tile[tx][ty + 8 * k]);
}

// ---------------- GEMM: C[M,N] = A[M,K] * B_T[N,K]^T  (bf16 in) ----------------
// 256x128 tile, 256 threads (4 waves = 2 wm x 2 wn), per-wave C block 128x64.
// K-tiles of BK=32; 3 A-bufs + 3 B-bufs rotate; prefetch distance 2; counted
// vmcnt(4).  LDS swizzle (both sides): within a 128B row-pair, 16B chunk at
// logical (row,chunk) lives at pos = (((row&1)<<2)|chunk) ^ ((row>>1)&7).
// OUT_MODE 1: bf16 out to HEAD-MAJOR qkv [8][32768][192]: 64-col group
//   grp = bx*2+wn -> z=grp>>3 (q/k/v), h=grp&7; addr = h*6291456 + row*192 + z*64.
// OUT_MODE 0: f32 + bias, standard [M][N].
template<int OUT_MODE, int KDIM>
__global__ __launch_bounds__(256, 2) void gemm256(
    const uint16_t* __restrict__ A, const uint16_t* __restrict__ B,
    void* __restrict__ C, const float* __restrict__ bias, int N, int nbx) {
  constexpr int NT = KDIM / 32;
  __shared__ __align__(16) uint16_t ldsA[3][8192];   // 3 x 16KB
  __shared__ __align__(16) uint16_t ldsB[3][4096];   // 3 x 8KB
  __shared__ __align__(16) uint16_t ldsO[4][1024];   // 8KB epilogue transpose
  const int tid = threadIdx.x;
  const int w = tid >> 6, l = tid & 63;
  const int lr = l & 15, kc = l >> 4;
  const int wm = w >> 1, wn = w & 1;
  const int cpx = gridDim.x >> 3;
  const int id = blockIdx.x;
  const int swz = (id & 7) * cpx + (id >> 3);
  const int by = swz / nbx, bx = swz - by * nbx;
  const int mBase = by * 256, nBase = bx * 128;
  // staging source (pre-swizzled): dest lane l writes 16B at linear pos l;
  // row-pair rp = l>>3, slot p = l&7; logical ((row&1)<<2)|chunk = p ^ (rp&7).
  const int g8 = l >> 3;
  const int sub = (l & 7) ^ g8;
  const uint16_t* gA = A + (size_t)(mBase + w * 64 + g8 * 2 + (sub >> 2)) * KDIM + (sub & 3) * 8;
  const uint16_t* gB = B + (size_t)(nBase + w * 32 + g8 * 2 + (sub >> 2)) * KDIM + (sub & 3) * 8;
  int offA[8], offB[4];
  #pragma unroll
  for (int m = 0; m < 8; ++m) {
    int row = wm * 128 + m * 16 + lr;
    int rp = row >> 1, sb = ((row & 1) << 2) | kc;
    offA[m] = rp * 128 + ((sb ^ (rp & 7)) << 4);
  }
  #pragma unroll
  for (int n = 0; n < 4; ++n) {
    int row = wn * 64 + n * 16 + lr;
    int rp = row >> 1, sb = ((row & 1) << 2) | kc;
    offB[n] = rp * 128 + ((sb ^ (rp & 7)) << 4);
  }
  f32x4 acc[8][4] = {};

#define STAGE_A(t, bf) do { \
    uint16_t* d = &ldsA[bf][w * 2048]; \
    const uint16_t* s = gA + (t) * 32; \
    __builtin_amdgcn_global_load_lds(AS1P(s),              AS3P(d),        16, 0, 0); \
    __builtin_amdgcn_global_load_lds(AS1P(s + 16 * KDIM),  AS3P(d + 512),  16, 0, 0); \
    __builtin_amdgcn_global_load_lds(AS1P(s + 32 * KDIM),  AS3P(d + 1024), 16, 0, 0); \
    __builtin_amdgcn_global_load_lds(AS1P(s + 48 * KDIM),  AS3P(d + 1536), 16, 0, 0); \
  } while (0)
#define STAGE_B(t, bf) do { \
    uint16_t* d = &ldsB[bf][w * 1024]; \
    const uint16_t* s = gB + (t) * 32; \
    __builtin_amdgcn_global_load_lds(AS1P(s),              AS3P(d),        16, 0, 0); \
    __builtin_amdgcn_global_load_lds(AS1P(s + 16 * KDIM),  AS3P(d + 512),  16, 0, 0); \
  } while (0)

  // prologue: tiles 0,1 (A0,B0,A1,B1 = 12 loads); vmcnt(6) -> tile 0 resident
  STAGE_A(0, 0); STAGE_B(0, 0);
  STAGE_A(1, 1); STAGE_B(1, 1);
  asm volatile("s_waitcnt vmcnt(6)" ::: "memory");
  __builtin_amdgcn_s_barrier();

  #pragma unroll
  for (int t = 0; t < NT; ++t) {
    const int bi = t % 3;
    const int si = (t + 2) % 3;
    const char* bufA = (const char*)&ldsA[bi][0];
    const char* bufB = (const char*)&ldsB[bi][0];
    // ---------------- phase 1 ----------------
    if (t + 2 < NT) STAGE_A(t + 2, si);
    // counted wait: tile t+1 resident (own loads; barrier propagates cross-wave)
    if (t + 2 < NT) asm volatile("s_waitcnt vmcnt(4)" ::: "memory");
    else            asm volatile("s_waitcnt vmcnt(0)" ::: "memory");
    bf16x8 a0 = *(const bf16x8*)(bufA + offA[0]);
    bf16x8 a1 = *(const bf16x8*)(bufA + offA[1]);
    bf16x8 a2 = *(const bf16x8*)(bufA + offA[2]);
    bf16x8 a3 = *(const bf16x8*)(bufA + offA[3]);
    bf16x8 b0 = *(const bf16x8*)(bufB + offB[0]);
    bf16x8 b1 = *(const bf16x8*)(bufB + offB[1]);
    bf16x8 b2 = *(const bf16x8*)(bufB + offB[2]);
    bf16x8 b3 = *(const bf16x8*)(bufB + offB[3]);
    __builtin_amdgcn_sched_barrier(0);
    __builtin_amdgcn_s_barrier();
    asm volatile("s_waitcnt lgkmcnt(0)" ::: "memory");
    __builtin_amdgcn_sched_barrier(0);
    __builtin_amdgcn_s_setprio(1);
    acc[0][0] = __builtin_amdgcn_mfma_f32_16x16x32_bf16(a0, b0, acc[0][0], 0, 0, 0);
    acc[0][1] = __builtin_amdgcn_mfma_f32_16x16x32_bf16(a0, b1, acc[0][1], 0, 0, 0);
    acc[0][2] = __builtin_amdgcn_mfma_f32_16x16x32_bf16(a0, b2, acc[0][2], 0, 0, 0);
    acc[0][3] = __builtin_amdgcn_mfma_f32_16x16x32_bf16(a0, b3, acc[0][3], 0, 0, 0);
    acc[1][0] = __builtin_amdgcn_mfma_f32_16x16x32_bf16(a1, b0, acc[1][0], 0, 0, 0);
    acc[1][1] = __builtin_amdgcn_mfma_f32_16x16x32_bf16(a1, b1, acc[1][1], 0, 0, 0);
    acc[1][2] = __builtin_amdgcn_mfma_f32_16x16x32_bf16(a1, b2, acc[1][2], 0, 0, 0);
    acc[1][3] = __builtin_amdgcn_mfma_f32_16x16x32_bf16(a1, b3, acc[1][3], 0, 0, 0);
    acc[2][0] = __builtin_amdgcn_mfma_f32_16x16x32_bf16(a2, b0, acc[2][0], 0, 0, 0);
    acc[2][1] = __builtin_amdgcn_mfma_f32_16x16x32_bf16(a2, b1, acc[2][1], 0, 0, 0);
    acc[2][2] = __builtin_amdgcn_mfma_f32_16x16x32_bf16(a2, b2, acc[2][2], 0, 0, 0);
    acc[2][3] = __builtin_amdgcn_mfma_f32_16x16x32_bf16(a2, b3, acc[2][3], 0, 0, 0);
    acc[3][0] = __builtin_amdgcn_mfma_f32_16x16x32_bf16(a3, b0, acc[3][0], 0, 0, 0);
    acc[3][1] = __builtin_amdgcn_mfma_f32_16x16x32_bf16(a3, b1, acc[3][1], 0, 0, 0);
    acc[3][2] = __builtin_amdgcn_mfma_f32_16x16x32_bf16(a3, b2, acc[3][2], 0, 0, 0);
    acc[3][3] = __builtin_amdgcn_mfma_f32_16x16x32_bf16(a3, b3, acc[3][3], 0, 0, 0);
    __builtin_amdgcn_s_setprio(0);
    __builtin_amdgcn_sched_barrier(0);
    __builtin_amdgcn_s_barrier();
    // ---------------- phase 2 ----------------
    if (t + 2 < NT) STAGE_B(t + 2, si);
    bf16x8 a4 = *(const bf16x8*)(bufA + offA[4]);
    bf16x8 a5 = *(const bf16x8*)(bufA + offA[5]);
    bf16x8 a6 = *(const bf16x8*)(bufA + offA[6]);
    bf16x8 a7 = *(const bf16x8*)(bufA + offA[7]);
    __builtin_amdgcn_sched_barrier(0);
    __builtin_amdgcn_s_barrier();
    asm volatile("s_waitcnt lgkmcnt(0)" ::: "memory");
    __builtin_amdgcn_sched_barrier(0);
    __builtin_amdgcn_s_setprio(1);
    acc[4][0] = __builtin_amdgcn_mfma_f32_16x16x32_bf16(a4, b0, acc[4][0], 0, 0, 0);
    acc[4][1] = __builtin_amdgcn_mfma_f32_16x16x32_bf16(a4, b1, acc[4][1], 0, 0, 0);
    acc[4][2] = __builtin_amdgcn_mfma_f32_16x16x32_bf16(a4, b2, acc[4][2], 0, 0, 0);
    acc[4][3] = __builtin_amdgcn_mfma_f32_16x16x32_bf16(a4, b3, acc[4][3], 0, 0, 0);
    acc[5][0] = __builtin_amdgcn_mfma_f32_16x16x32_bf16(a5, b0, acc[5][0], 0, 0, 0);
    acc[5][1] = __builtin_amdgcn_mfma_f32_16x16x32_bf16(a5, b1, acc[5][1], 0, 0, 0);
    acc[5][2] = __builtin_amdgcn_mfma_f32_16x16x32_bf16(a5, b2, acc[5][2], 0, 0, 0);
    acc[5][3] = __builtin_amdgcn_mfma_f32_16x16x32_bf16(a5, b3, acc[5][3], 0, 0, 0);
    acc[6][0] = __builtin_amdgcn_mfma_f32_16x16x32_bf16(a6, b0, acc[6][0], 0, 0, 0);
    acc[6][1] = __builtin_amdgcn_mfma_f32_16x16x32_bf16(a6, b1, acc[6][1], 0, 0, 0);
    acc[6][2] = __builtin_amdgcn_mfma_f32_16x16x32_bf16(a6, b2, acc[6][2], 0, 0, 0);
    acc[6][3] = __builtin_amdgcn_mfma_f32_16x16x32_bf16(a6, b3, acc[6][3], 0, 0, 0);
    acc[7][0] = __builtin_amdgcn_mfma_f32_16x16x32_bf16(a7, b0, acc[7][0], 0, 0, 0);
    acc[7][1] = __builtin_amdgcn_mfma_f32_16x16x32_bf16(a7, b1, acc[7][1], 0, 0, 0);
    acc[7][2] = __builtin_amdgcn_mfma_f32_16x16x32_bf16(a7, b2, acc[7][2], 0, 0, 0);
    acc[7][3] = __builtin_amdgcn_mfma_f32_16x16x32_bf16(a7, b3, acc[7][3], 0, 0, 0);
    __builtin_amdgcn_s_setprio(0);
    __builtin_amdgcn_sched_barrier(0);
    __builtin_amdgcn_s_barrier();
  }
#undef STAGE_A
#undef STAGE_B
  if (OUT_MODE == 1) {
    // epilogue via per-wave LDS transpose -> coalesced b128 stores into
    // head-major qkv: grp = bx*2+wn (64-col group), z = grp>>3, h = grp&7.
    uint16_t* oW = &ldsO[w][0];
    const int t2 = l >> 3, c2 = l & 7;
    const int grp = bx * 2 + wn;
    const int z = grp >> 3, h = grp & 7;
    uint16_t* gO = (uint16_t*)C + (size_t)h * 6291456 +
                   (size_t)(mBase + wm * 128 + t2) * 192 + z * 64 + c2 * 8;
    #pragma unroll
    for (int m = 0; m < 8; ++m) {
      #pragma unroll
      for (int n = 0; n < 4; ++n)
        #pragma unroll
        for (int r = 0; r < 4; ++r) {
          const int tt = kc * 4 + r;
          const int d = n * 16 + lr;
          const int col = (((d >> 3) ^ (tt & 7)) << 3) | (d & 7);
          oW[tt * 64 + col] = f2bf(acc[m][n][r]);
        }
      asm volatile("s_waitcnt lgkmcnt(0)" ::: "memory");
      __builtin_amdgcn_sched_barrier(0);
      bf16x8 s0 = *(const bf16x8*)(oW + t2 * 64 + (((c2 ^ (t2 & 7)) << 3)));
      bf16x8 s1 = *(const bf16x8*)(oW + (8 + t2) * 64 + (((c2 ^ (t2 & 7)) << 3)));
      *(bf16x8*)(gO + (size_t)(m * 16) * 192) = s0;
      *(bf16x8*)(gO + (size_t)(m * 16 + 8) * 192) = s1;
      asm volatile("s_waitcnt lgkmcnt(0)" ::: "memory");
      __builtin_amdgcn_sched_barrier(0);
    }
  } else {
    #pragma unroll
    for (int m = 0; m < 8; ++m)
      #pragma unroll
      for (int n = 0; n < 4; ++n) {
        const int col = nBase + wn * 64 + n * 16 + lr;
        #pragma unroll
        for (int r = 0; r < 4; ++r) {
          const int row = mBase + wm * 128 + m * 16 + kc * 4 + r;
          ((float*)C)[(size_t)row * N + col] = acc[m][n][r] + bias[col];
        }
      }
  }
}

// ---------------- attention: 8 waves/block, one wave per (b,h) ----------------
// qkv head-major [8][32768][192]: per (b,h) the 16 rows are contiguous 384B
// chunks (q bytes [0,128), k [128,256), v [256,384)).
// vT stride 16 u16 (32B): LDS ~35KB/block -> 4 blocks/CU.
__global__ __launch_bounds__(512) void attn_kernel(
    const uint16_t* __restrict__ qkv,
    const float* __restrict__ relk, const float* __restrict__ relv,
    uint16_t* __restrict__ outA) {
  __shared__ __align__(16) uint16_t relkS[33 * 72];
  __shared__ __align__(16) uint16_t relvT[64 * 40];
  __shared__ __align__(16) uint16_t vT[8][64 * 16];   // per-wave; reused as oW
  __shared__ float attnS[8][16 * 17];
  const int tid = threadIdx.x;
  for (int e = tid; e < 33 * 64; e += 512) {
    int j = e >> 6, d = e & 63;
    relkS[j * 72 + d] = f2bf(relk[e]);
    relvT[d * 40 + j] = f2bf(relv[e]);
  }
  const int w = tid >> 6, l = tid & 63;
  const int bh = blockIdx.x * 8 + w;
  const int b = bh >> 3, h = bh & 7;
  const int lr = l & 15, kc = l >> 4;
  const uint16_t* base = qkv + (size_t)h * 6291456 + (size_t)(b * 16) * 192;
  const uint16_t* qrow = base + lr * 192;
  bf16x8 aq0 = *(const bf16x8*)(qrow + kc * 8);
  bf16x8 aq1 = *(const bf16x8*)(qrow + 32 + kc * 8);
  const uint16_t* krow = qrow + 64;
  bf16x8 bk0 = *(const bf16x8*)(krow + kc * 8);
  bf16x8 bk1 = *(const bf16x8*)(krow + 32 + kc * 8);
  {
    const int s = l >> 2, dg = l & 3;
    const uint16_t* vrow = base + s * 192 + 128 + dg * 16;
    uint4 v0 = *(const uint4*)vrow;
    uint4 v1 = *(const uint4*)(vrow + 8);
    uint16_t tmp[16];
    *(uint4*)(tmp) = v0; *(uint4*)(tmp + 8) = v1;
    #pragma unroll
    for (int i = 0; i < 16; ++i)
      vT[w][(dg * 16 + i) * 16 + s] = tmp[i];
  }
  __syncthreads();
  const f32x4 zero = {0.f, 0.f, 0.f, 0.f};
  f32x4 sim = __builtin_amdgcn_mfma_f32_16x16x32_bf16(aq0, bk0, zero, 0, 0, 0);
  sim = __builtin_amdgcn_mfma_f32_16x16x32_bf16(aq1, bk1, sim, 0, 0, 0);
  bf16x8 rka0 = *(const bf16x8*)(relkS + lr * 72 + kc * 8);
  bf16x8 rka1 = *(const bf16x8*)(relkS + lr * 72 + 32 + kc * 8);
  bf16x8 rkb0 = *(const bf16x8*)(relkS + (16 + lr) * 72 + kc * 8);
  bf16x8 rkb1 = *(const bf16x8*)(relkS + (16 + lr) * 72 + 32 + kc * 8);
  f32x4 rqa = __builtin_amdgcn_mfma_f32_16x16x32_bf16(aq0, rka0, zero, 0, 0, 0);
  rqa = __builtin_amdgcn_mfma_f32_16x16x32_bf16(aq1, rka1, rqa, 0, 0, 0);
  f32x4 rqb = __builtin_amdgcn_mfma_f32_16x16x32_bf16(aq0, rkb0, zero, 0, 0, 0);
  rqb = __builtin_amdgcn_mfma_f32_16x16x32_bf16(aq1, rkb1, rqb, 0, 0, 0);
  #pragma unroll
  for (int r = 0; r < 4; ++r) {
    const int t = kc * 4 + r;
    const int j = lr - t + 16;
    const int src = (l & 48) | (j & 15);
    const float va = __shfl(rqa[r], src, 64);
    const float vb = __shfl(rqb[r], src, 64);
    const float rqv = (j < 16) ? va : vb;
    float sv = (sim[r] + rqv) * 0.125f;
    float m = sv;
    m = fmaxf(m, __shfl_xor(m, 1, 64));
    m = fmaxf(m, __shfl_xor(m, 2, 64));
    m = fmaxf(m, __shfl_xor(m, 4, 64));
    m = fmaxf(m, __shfl_xor(m, 8, 64));
    const float p = __expf(sv - m);
    float su = p;
    su += __shfl_xor(su, 1, 64);
    su += __shfl_xor(su, 2, 64);
    su += __shfl_xor(su, 4, 64);
    su += __shfl_xor(su, 8, 64);
    attnS[w][t * 17 + lr] = p / su;
  }
  __syncthreads();
  const float* aS = attnS[w];
  bf16x8 attnA, w2A;
  #pragma unroll
  for (int i = 0; i < 8; ++i) {
    const int s1 = kc * 8 + i;
    attnA[i] = (s1 < 16) ? (short)f2bf(aS[lr * 17 + s1]) : (short)0;
    const int s2 = s1 + lr - 16;
    w2A[i] = (s2 >= 0 && s2 < 16) ? (short)f2bf(aS[lr * 17 + s2]) : (short)0;
  }
  f32x4 o[4];
  #pragma unroll
  for (int dt = 0; dt < 4; ++dt) {
    bf16x8 vf  = *(const bf16x8*)(&vT[w][(dt * 16 + lr) * 16 + (kc & 1) * 8]);
    bf16x8 rvf = *(const bf16x8*)(&relvT[(dt * 16 + lr) * 40 + kc * 8]);
    o[dt] = __builtin_amdgcn_mfma_f32_16x16x32_bf16(w2A, rvf, zero, 0, 0, 0);
    o[dt] = __builtin_amdgcn_mfma_f32_16x16x32_bf16(attnA, vf, o[dt], 0, 0, 0);
  }
  // coalesced store: transpose [16][64] through LDS (overlaid on dead vT[w])
  asm volatile("s_waitcnt lgkmcnt(0)" ::: "memory");
  __builtin_amdgcn_sched_barrier(0);
  uint16_t* oW = &vT[w][0];                   // 1024 u16, exactly [16][64]
  #pragma unroll
  for (int dt = 0; dt < 4; ++dt)
    #pragma unroll
    for (int r = 0; r < 4; ++r) {
      const int t = kc * 4 + r;
      const int chunk = dt * 2 + (lr >> 3);
      oW[t * 64 + ((chunk ^ (t & 7)) << 3) + (lr & 7)] = f2bf(o[dt][r]);
    }
  asm volatile("s_waitcnt lgkmcnt(0)" ::: "memory");
  __builtin_amdgcn_sched_barrier(0);
  const int t2 = l >> 3, c2 = l & 7;
  bf16x8 s0 = *(const bf16x8*)(oW + t2 * 64 + ((c2 ^ (t2 & 7)) << 3));
  bf16x8 s1 = *(const bf16x8*)(oW + (8 + t2) * 64 + ((c2 ^ (t2 & 7)) << 3));
  *(bf16x8*)(outA + (size_t)(b * 16 + t2) * 512 + h * 64 + c2 * 8) = s0;
  *(bf16x8*)(outA + (size_t)(b * 16 + 8 + t2) * 512 + h * 64 + c2 * 8) = s1;
}

// ---------------------------------------------------------------------------
extern "C" void kernel_launch(void* const* d_in, const int* in_sizes, int n_in,
                              void* d_out, int out_size, void* d_ws, size_t ws_size,
                              hipStream_t stream) {
  const float* x    = (const float*)d_in[0];
  const float* Wq   = (const float*)d_in[1];
  const float* Wk   = (const float*)d_in[2];
  const float* Wv   = (const float*)d_in[3];
  const float* Wo   = (const float*)d_in[4];
  const float* bo   = (const float*)d_in[5];
  const float* relk = (const float*)d_in[6];
  const float* relv = (const float*)d_in[7];

  char* ws = (char*)d_ws;
  uint16_t* qkv   = (uint16_t*)ws;                    // head-major [8][32768][192]
  uint16_t* xbf   = (uint16_t*)(ws + 100663296);      // [32768][512] bf16
  uint16_t* WqkvT = (uint16_t*)(ws + 134217728);      // [1536][512] bf16 (B^T)
  uint16_t* WoT   = (uint16_t*)(ws + 135790592);      // [512][512] bf16 (B^T)
  uint16_t* attnO = xbf;                              // reuse: x_bf dead after GEMM1

  // cast + weight transposes fused in one launch (independent work)
  prep_kernel<<<9216, 256, 0, stream>>>(x, xbf, Wq, Wk, Wv, Wo, WqkvT, WoT);
  // qkv = x_bf @ [Wq|Wk|Wv]  (M=32768, N=1536, K=512), head-major bf16 out
  gemm256<1, 512><<<dim3(1536), dim3(256), 0, stream>>>(xbf, WqkvT, (void*)qkv, nullptr, 1536, 12);
  // attention (reads head-major qkv, writes attn_out bf16 [32768][512])
  attn_kernel<<<2048, 512, 0, stream>>>(qkv, relk, relv, attnO);
  // out = attn_out @ Wo + bo  (fp32 out, M=32768, N=512, K=512)
  gemm256<0, 512><<<dim3(512), dim3(256), 0, stream>>>(attnO, WoT, d_out, bo, 512, 4);
}